// Round 1
// baseline (1022.026 us; speedup 1.0000x reference)
//
#include <hip/hip_runtime.h>
#include <math.h>

#define BB 8
#define LL 2048
#define DD 256
#define TQ 32
#define TK 64
#define FR 16

// XOR swizzle on float4-groups: element (row, group g) stored at group g ^ hsw(row).
// Makes row-crossing b128 reads spread across bank-starts; involution, so read = same formula.
__device__ __forceinline__ int hsw(int r) { return ((r & 7) ^ ((r >> 3) & 7)); }

__device__ __forceinline__ float f4c(const float4& v, int i) {
    return i == 0 ? v.x : (i == 1 ? v.y : (i == 2 ? v.z : v.w));
}

// ---------------- Flash attention: aug[b,i,:] = softmax_j(c2[b,i]*c1[b,j], mask) @ c1[b] ----
__global__ __launch_bounds__(256, 2)
void attn_kernel(const float* __restrict__ c1, const float* __restrict__ c2,
                 const unsigned char* __restrict__ cmask, float* __restrict__ aug)
{
    __shared__ float Ks[TK * DD];   // c1 key/value tile, swizzled [64][256]
    __shared__ float Ps[TQ * TK];   // P tile row-major [32][64]

    const int tid = threadIdx.x;
    const int tx = tid & 31;        // 0..31 : S cols {tx, tx+32}, O col-groups {tx, tx+32}
    const int ty = tid >> 5;        // 0..7  : rows r0..r0+3
    const int n  = blockIdx.x;
    const int qt = n & 63;          // qtile fast, batch slow -> XCD L2 locality on c1[b]
    const int b  = n >> 6;
    const int q0 = qt * TQ;
    const int r0 = ty * 4;

    const float* c1b = c1 + (size_t)b * LL * DD;
    const float* c2b = c2 + (size_t)b * LL * DD;
    const unsigned char* mb = cmask + (size_t)b * LL;

    const float* qp[4];
#pragma unroll
    for (int i = 0; i < 4; ++i) qp[i] = c2b + (size_t)(q0 + r0 + i) * DD;

    const int hc0 = hsw(tx);
    const int hc1 = hsw(tx + 32);

    float o[4][8];
    float m[4], l[4];
#pragma unroll
    for (int i = 0; i < 4; ++i) {
        m[i] = -INFINITY; l[i] = 0.f;
#pragma unroll
        for (int q = 0; q < 8; ++q) o[i][q] = 0.f;
    }

    for (int kt = 0; kt < LL / TK; ++kt) {
        const int k0 = kt * TK;
        // ---- stage c1 tile (64 rows x 256) into LDS, swizzled; coalesced 1KB-row loads
#pragma unroll
        for (int i = 0; i < 16; ++i) {
            int f = i * 256 + tid;          // 4096 float4 groups
            int row = f >> 6, g = f & 63;
            float4 v = *(const float4*)(c1b + (size_t)(k0 + row) * DD + (g << 2));
            *(float4*)(&Ks[row * 256 + ((g ^ hsw(row)) << 2)]) = v;
        }
        __syncthreads();

        // ---- S = Q K^T fragment (4 rows x 2 cols), Q streamed from global/L1
        float s[4][2];
#pragma unroll
        for (int i = 0; i < 4; ++i) { s[i][0] = 0.f; s[i][1] = 0.f; }

#pragma unroll 4
        for (int g = 0; g < 64; ++g) {
            float4 kk0 = *(const float4*)(&Ks[tx * 256 + ((g ^ hc0) << 2)]);
            float4 kk1 = *(const float4*)(&Ks[(tx + 32) * 256 + ((g ^ hc1) << 2)]);
#pragma unroll
            for (int i = 0; i < 4; ++i) {
                float4 q4 = *(const float4*)(qp[i] + (g << 2));
                s[i][0] += q4.x * kk0.x + q4.y * kk0.y + q4.z * kk0.z + q4.w * kk0.w;
                s[i][1] += q4.x * kk1.x + q4.y * kk1.y + q4.z * kk1.z + q4.w * kk1.w;
            }
        }

        // ---- masks + online softmax update
        const int gc0 = k0 + tx, gc1 = k0 + tx + 32;
        const bool mk0 = (mb[gc0] != 0), mk1 = (mb[gc1] != 0);
#pragma unroll
        for (int i = 0; i < 4; ++i) {
            const int gr = q0 + r0 + i;
            float s0 = (mk0 || gc0 == gr) ? -INFINITY : s[i][0];
            float s1 = (mk1 || gc1 == gr) ? -INFINITY : s[i][1];
            float mt = fmaxf(s0, s1);
#pragma unroll
            for (int off = 1; off < 32; off <<= 1)
                mt = fmaxf(mt, __shfl_xor(mt, off, 64));   // reduce over 32 tx lanes (half-wave)
            float mn = fmaxf(m[i], mt);
            float alpha = (m[i] == -INFINITY) ? 0.f : __expf(m[i] - mn);
            float p0 = (s0 == -INFINITY) ? 0.f : __expf(s0 - mn);
            float p1 = (s1 == -INFINITY) ? 0.f : __expf(s1 - mn);
            float rs = p0 + p1;
#pragma unroll
            for (int off = 1; off < 32; off <<= 1)
                rs += __shfl_xor(rs, off, 64);
            l[i] = l[i] * alpha + rs;
            m[i] = mn;
#pragma unroll
            for (int q = 0; q < 8; ++q) o[i][q] *= alpha;
            Ps[(r0 + i) * TK + tx] = p0;
            Ps[(r0 + i) * TK + tx + 32] = p1;
        }
        __syncthreads();

        // ---- O += P @ V  (V == same c1 tile in Ks)
#pragma unroll 2
        for (int j4 = 0; j4 < TK; j4 += 4) {
            float pr[4][4];
#pragma unroll
            for (int i = 0; i < 4; ++i) {
                float4 t = *(const float4*)(&Ps[(r0 + i) * TK + j4]);
                pr[i][0] = t.x; pr[i][1] = t.y; pr[i][2] = t.z; pr[i][3] = t.w;
            }
#pragma unroll
            for (int jj = 0; jj < 4; ++jj) {
                int j = j4 + jj;
                int g0 = (tx ^ hsw(j));
                float4 v0 = *(const float4*)(&Ks[j * 256 + (g0 << 2)]);
                float4 v1 = *(const float4*)(&Ks[j * 256 + ((g0 + 32) << 2)]);
#pragma unroll
                for (int i = 0; i < 4; ++i) {
                    float p = pr[i][jj];
                    o[i][0] += p * v0.x; o[i][1] += p * v0.y;
                    o[i][2] += p * v0.z; o[i][3] += p * v0.w;
                    o[i][4] += p * v1.x; o[i][5] += p * v1.y;
                    o[i][6] += p * v1.z; o[i][7] += p * v1.w;
                }
            }
        }
        __syncthreads();
    }

    // ---- write aug (cols d = 4*tx + {0..3} and 4*tx + 128 + {0..3})
#pragma unroll
    for (int i = 0; i < 4; ++i) {
        float inv = 1.0f / l[i];
        size_t base = ((size_t)b * LL + q0 + r0 + i) * DD;
        float4 w0 = make_float4(o[i][0] * inv, o[i][1] * inv, o[i][2] * inv, o[i][3] * inv);
        float4 w1 = make_float4(o[i][4] * inv, o[i][5] * inv, o[i][6] * inv, o[i][7] * inv);
        *(float4*)(aug + base + (tx << 2)) = w0;
        *(float4*)(aug + base + (tx << 2) + 128) = w1;
    }
}

// ---------------- Fusion: out = g*tanh(zWf+bf) + (1-g)*c2, g = sigmoid(zWg+bg) --------------
__global__ __launch_bounds__(256, 2)
void fusion_kernel(const float* __restrict__ c2, const float* __restrict__ aug,
                   const float* __restrict__ Wf, const float* __restrict__ bf,
                   const float* __restrict__ Wg, const float* __restrict__ bg,
                   float* __restrict__ out)
{
    __shared__ float zs[FR][1024];
    __shared__ float gpart[4][FR];
    __shared__ float gv[FR];

    const int tid = threadIdx.x;
    const size_t row0 = (size_t)blockIdx.x * FR;

    // ---- build z tile: [c2, aug, c2*aug, c2-aug]
#pragma unroll
    for (int i = 0; i < 4; ++i) {
        int f = i * 256 + tid;          // 1024 float4 groups (16 rows x 64)
        int r = f >> 6, d4 = (f & 63) << 2;
        float4 a = *(const float4*)(c2 + (row0 + r) * DD + d4);
        float4 u = *(const float4*)(aug + (row0 + r) * DD + d4);
        *(float4*)(&zs[r][d4]) = a;
        *(float4*)(&zs[r][256 + d4]) = u;
        *(float4*)(&zs[r][512 + d4]) = make_float4(a.x * u.x, a.y * u.y, a.z * u.z, a.w * u.w);
        *(float4*)(&zs[r][768 + d4]) = make_float4(a.x - u.x, a.y - u.y, a.z - u.z, a.w - u.w);
    }
    __syncthreads();

    // ---- gate dot: each thread covers k = 4*tid..4*tid+3 for all 16 rows
    {
        float4 wg = *(const float4*)(Wg + (tid << 2));
        float gp[FR];
#pragma unroll
        for (int r = 0; r < FR; ++r) {
            float4 z = *(const float4*)(&zs[r][tid << 2]);
            gp[r] = z.x * wg.x + z.y * wg.y + z.z * wg.z + z.w * wg.w;
        }
#pragma unroll
        for (int off = 1; off < 64; off <<= 1) {
#pragma unroll
            for (int r = 0; r < FR; ++r) gp[r] += __shfl_xor(gp[r], off, 64);
        }
        if ((tid & 63) == 0) {
            int w = tid >> 6;
#pragma unroll
            for (int r = 0; r < FR; ++r) gpart[w][r] = gp[r];
        }
    }
    __syncthreads();
    if (tid < FR) {
        float gs = gpart[0][tid] + gpart[1][tid] + gpart[2][tid] + gpart[3][tid] + bg[0];
        gv[tid] = 1.0f / (1.0f + __expf(-gs));
    }
    __syncthreads();

    // ---- fusion GEMM: 4 rows x 4 cols per thread, k over 1024
    const int d0  = (tid & 63) << 2;   // output col base
    const int rr0 = (tid >> 6) << 2;   // row base (wave-uniform)
    float acc[4][4] = {{0.f}};
    for (int k = 0; k < 1024; k += 4) {
        float4 z[4];
#pragma unroll
        for (int i = 0; i < 4; ++i) z[i] = *(const float4*)(&zs[rr0 + i][k]);
#pragma unroll
        for (int kk = 0; kk < 4; ++kk) {
            float4 w = *(const float4*)(Wf + (size_t)(k + kk) * DD + d0);
#pragma unroll
            for (int i = 0; i < 4; ++i) {
                float zz = f4c(z[i], kk);
                acc[i][0] += zz * w.x; acc[i][1] += zz * w.y;
                acc[i][2] += zz * w.z; acc[i][3] += zz * w.w;
            }
        }
    }

    // ---- epilogue
    float4 bfv = *(const float4*)(bf + d0);
#pragma unroll
    for (int i = 0; i < 4; ++i) {
        int r = rr0 + i;
        float g = gv[r];
        float4 cc = *(const float4*)(&zs[r][d0]);   // seg0 == c2
        float4 res;
        res.x = g * tanhf(acc[i][0] + bfv.x) + (1.f - g) * cc.x;
        res.y = g * tanhf(acc[i][1] + bfv.y) + (1.f - g) * cc.y;
        res.z = g * tanhf(acc[i][2] + bfv.z) + (1.f - g) * cc.z;
        res.w = g * tanhf(acc[i][3] + bfv.w) + (1.f - g) * cc.w;
        *(float4*)(out + (row0 + r) * DD + d0) = res;
    }
}

extern "C" void kernel_launch(void* const* d_in, const int* in_sizes, int n_in,
                              void* d_out, int out_size, void* d_ws, size_t ws_size,
                              hipStream_t stream)
{
    const float* c1 = (const float*)d_in[0];
    const float* c2 = (const float*)d_in[1];
    const unsigned char* cmask = (const unsigned char*)d_in[2];
    const float* Wf = (const float*)d_in[3];
    const float* bf = (const float*)d_in[4];
    const float* Wg = (const float*)d_in[5];
    const float* bg = (const float*)d_in[6];
    // d_in[7] = flag (always 1 -> forward_fuse path)

    float* aug = (float*)d_ws;   // B*L*D fp32 = 16 MB scratch
    float* out = (float*)d_out;

    attn_kernel<<<dim3(BB * (LL / TQ)), dim3(256), 0, stream>>>(c1, c2, cmask, aug);
    fusion_kernel<<<dim3((BB * LL) / FR), dim3(256), 0, stream>>>(c2, aug, Wf, bf, Wg, bg, out);
}

// Round 2
// 381.650 us; speedup vs baseline: 2.6779x; 2.6779x over previous
//
#include <hip/hip_runtime.h>
#include <math.h>

#define BB 8
#define LL 2048
#define DD 256
#define FR 16

typedef float  f4_t __attribute__((ext_vector_type(4)));
typedef short  s8_t __attribute__((ext_vector_type(8)));

union S8U { s8_t v; unsigned u[4]; };

__device__ __forceinline__ unsigned bitsf(float x){ union{float f; unsigned u;} c; c.f=x; return c.u; }
__device__ __forceinline__ float fbits(unsigned u){ union{float f; unsigned u;} c; c.u=u; return c.f; }
// pack two fp32 -> two bf16 (truncate), elem0 in low half
__device__ __forceinline__ unsigned pkhi(float a, float b){ return (bitsf(a)>>16) | (bitsf(b)&0xffff0000u); }
// pack two fp32 -> two bf16 (round-nearest-ish)
__device__ __forceinline__ unsigned pkrn(float a, float b){
    unsigned ua = bitsf(a) + 0x8000u, ub = bitsf(b) + 0x8000u;
    return (ua>>16) | (ub&0xffff0000u);
}
__device__ __forceinline__ float f4c(const float4& v, int i) {
    return i == 0 ? v.x : (i == 1 ? v.y : (i == 2 ? v.z : v.w));
}

// sigma: row e (0..31) of the key tile -> Vperm slot; makes P's MFMA C/D layout
// directly usable as the PV A-operand (slot k=8q+4a+b holds j=16a+4q+b).
__device__ __forceinline__ int vslot(int e){ return ((e>>2)&3)*8 + ((e>>4)<<2) + (e&3); }

// ---------------- MFMA flash attention ----------------
// S^T = K.Q^T (3-pass bf16 hi/lo split), online softmax, aug = P.V (1 pass).
// Each wave owns 32 queries; block = 4 waves = 128 queries; keys [kb, kb+klen).
__global__ __launch_bounds__(256,1)
void attn_kernel(const float* __restrict__ c1, const float* __restrict__ c2,
                 const unsigned char* __restrict__ cmask,
                 float* __restrict__ o_out, float* __restrict__ mlp,
                 int klen, int split)
{
    __shared__ short Khi[32*264];   // key tile hi, pad 264 -> conflict-free b128
    __shared__ short Klo[32*264];   // key tile lo
    __shared__ short Vp [256*34];   // V^T, sigma-permuted cols, pitch 17 dwords

    const int tid  = threadIdx.x;
    const int lane = tid & 63;
    const int w    = tid >> 6;
    const int il   = lane & 15;
    const int quad = lane >> 4;

    const int blk  = blockIdx.x;
    const int bb   = blk & 7;           // batch -> XCD affinity
    const int qb   = (blk >> 3) & 15;
    const int half = split ? (blk >> 7) : 0;
    const int kb   = half * klen;

    const float* c1b = c1 + (size_t)bb * LL * DD;
    const float* c2b = c2 + (size_t)bb * LL * DD;
    const unsigned char* mb = cmask + (size_t)bb * LL;

    const int q0w = qb*128 + w*32;      // wave's first query (within batch)

    // ---- Q fragments (register-resident): hi/lo bf16 split
    s8_t qh[2][8], ql[2][8];
#pragma unroll
    for (int nt = 0; nt < 2; ++nt) {
        const float* qp = c2b + (size_t)(q0w + 16*nt + il)*DD + quad*8;
#pragma unroll
        for (int kd = 0; kd < 8; ++kd) {
            float4 x0 = *(const float4*)(qp + kd*32);
            float4 x1 = *(const float4*)(qp + kd*32 + 4);
            float e[8] = {x0.x,x0.y,x0.z,x0.w,x1.x,x1.y,x1.z,x1.w};
            S8U h, l;
#pragma unroll
            for (int p2 = 0; p2 < 4; ++p2) {
                float a = e[2*p2], b = e[2*p2+1];
                h.u[p2] = pkhi(a, b);
                float alo = a - fbits(bitsf(a)&0xffff0000u);
                float blo = b - fbits(bitsf(b)&0xffff0000u);
                l.u[p2] = pkhi(alo, blo);
            }
            qh[nt][kd] = h.v; ql[nt][kd] = l.v;
        }
    }

    // ---- accumulators / softmax state
    f4_t o[2][16];
#pragma unroll
    for (int mt = 0; mt < 2; ++mt)
#pragma unroll
        for (int n = 0; n < 16; ++n) o[mt][n] = (f4_t)0.0f;
    float m_s[2] = {-INFINITY, -INFINITY};
    float l_s[2] = {0.f, 0.f};

    const int NT = klen >> 5;
    float g[32];

    // stage tile 0: thread owns column d = tid, rows 0..31
#pragma unroll
    for (int e = 0; e < 32; ++e) g[e] = c1b[(size_t)(kb + e)*DD + tid];
#pragma unroll
    for (int e = 0; e < 32; ++e) {
        unsigned ub = bitsf(g[e]);
        Khi[e*264 + tid] = (short)(ub >> 16);
        float lo = g[e] - fbits(ub & 0xffff0000u);
        Klo[e*264 + tid] = (short)(bitsf(lo) >> 16);
    }
#pragma unroll
    for (int e = 0; e < 32; e += 2)
        ((unsigned*)Vp)[tid*17 + (vslot(e)>>1)] = pkrn(g[e], g[e+1]);
    __syncthreads();

    for (int kt = 0; kt < NT; ++kt) {
        const int k0 = kt << 5;
        // prefetch next tile's globals (overlaps MFMA below)
        if (kt + 1 < NT) {
#pragma unroll
            for (int e = 0; e < 32; ++e) g[e] = c1b[(size_t)(kb + k0 + 32 + e)*DD + tid];
        }

        // ---- S^T = K.Q^T, 3-pass split
        f4_t acc[2][2];
#pragma unroll
        for (int mj = 0; mj < 2; ++mj)
#pragma unroll
            for (int nt = 0; nt < 2; ++nt) acc[mj][nt] = (f4_t)0.0f;

#pragma unroll
        for (int kd = 0; kd < 8; ++kd) {
            s8_t ah0 = *(const s8_t*)&Khi[(il     )*264 + kd*32 + quad*8];
            s8_t ah1 = *(const s8_t*)&Khi[(16 + il)*264 + kd*32 + quad*8];
            s8_t al0 = *(const s8_t*)&Klo[(il     )*264 + kd*32 + quad*8];
            s8_t al1 = *(const s8_t*)&Klo[(16 + il)*264 + kd*32 + quad*8];
#pragma unroll
            for (int nt = 0; nt < 2; ++nt) {
                acc[0][nt] = __builtin_amdgcn_mfma_f32_16x16x32_bf16(ah0, qh[nt][kd], acc[0][nt], 0,0,0);
                acc[1][nt] = __builtin_amdgcn_mfma_f32_16x16x32_bf16(ah1, qh[nt][kd], acc[1][nt], 0,0,0);
                acc[0][nt] = __builtin_amdgcn_mfma_f32_16x16x32_bf16(al0, qh[nt][kd], acc[0][nt], 0,0,0);
                acc[1][nt] = __builtin_amdgcn_mfma_f32_16x16x32_bf16(al1, qh[nt][kd], acc[1][nt], 0,0,0);
                acc[0][nt] = __builtin_amdgcn_mfma_f32_16x16x32_bf16(ah0, ql[nt][kd], acc[0][nt], 0,0,0);
                acc[1][nt] = __builtin_amdgcn_mfma_f32_16x16x32_bf16(ah1, ql[nt][kd], acc[1][nt], 0,0,0);
            }
        }

        // ---- masks + online softmax (rows of S^T C/D are j; cols are i)
        unsigned mu[2];
#pragma unroll
        for (int mj = 0; mj < 2; ++mj)
            mu[mj] = *(const unsigned*)(mb + kb + k0 + 16*mj + 4*quad);

        f4_t p[2][2];
        float alpha_v[2];
#pragma unroll
        for (int nt = 0; nt < 2; ++nt) {
            const int ig = q0w + 16*nt + il;
            float mn = m_s[nt];
#pragma unroll
            for (int mj = 0; mj < 2; ++mj) {
#pragma unroll
                for (int b = 0; b < 4; ++b) {
                    int jg = kb + k0 + 16*mj + 4*quad + b;
                    float s = acc[mj][nt][b];
                    bool dead = (((mu[mj] >> (8*b)) & 0xff) != 0) || (jg == ig);
                    s = dead ? -INFINITY : s;
                    p[mj][nt][b] = s;
                    mn = fmaxf(mn, s);
                }
            }
            mn = fmaxf(mn, __shfl_xor(mn, 16, 64));
            mn = fmaxf(mn, __shfl_xor(mn, 32, 64));
            float al = __expf(m_s[nt] - mn);
            float rs = 0.f;
#pragma unroll
            for (int mj = 0; mj < 2; ++mj) {
#pragma unroll
                for (int b = 0; b < 4; ++b) {
                    float pe = __expf(p[mj][nt][b] - mn);
                    p[mj][nt][b] = pe;
                    rs += pe;
                }
            }
            rs += __shfl_xor(rs, 16, 64);
            rs += __shfl_xor(rs, 32, 64);
            l_s[nt] = l_s[nt]*al + rs;
            m_s[nt] = mn;
            alpha_v[nt] = al;
        }

        // ---- rescale O by alpha (broadcast alpha from S^T-layout lanes to O rows)
#pragma unroll
        for (int mt = 0; mt < 2; ++mt) {
            float am[4];
#pragma unroll
            for (int b = 0; b < 4; ++b) am[b] = __shfl(alpha_v[mt], 4*quad + b, 64);
#pragma unroll
            for (int n = 0; n < 16; ++n) {
#pragma unroll
                for (int b = 0; b < 4; ++b) o[mt][n][b] *= am[b];
            }
        }

        // ---- P (registers) -> PV A-fragments; B = sigma-permuted V^T from LDS
        s8_t ap[2];
#pragma unroll
        for (int mt = 0; mt < 2; ++mt) {
            S8U a;
            a.u[0] = pkrn(p[0][mt][0], p[0][mt][1]);
            a.u[1] = pkrn(p[0][mt][2], p[0][mt][3]);
            a.u[2] = pkrn(p[1][mt][0], p[1][mt][1]);
            a.u[3] = pkrn(p[1][mt][2], p[1][mt][3]);
            ap[mt] = a.v;
        }
#pragma unroll
        for (int n = 0; n < 16; ++n) {
            S8U bv;
#pragma unroll
            for (int dd = 0; dd < 4; ++dd)
                bv.u[dd] = ((const unsigned*)Vp)[(16*n + il)*17 + quad*4 + dd];
            o[0][n] = __builtin_amdgcn_mfma_f32_16x16x32_bf16(ap[0], bv.v, o[0][n], 0,0,0);
            o[1][n] = __builtin_amdgcn_mfma_f32_16x16x32_bf16(ap[1], bv.v, o[1][n], 0,0,0);
        }

        __syncthreads();
        if (kt + 1 < NT) {
#pragma unroll
            for (int e = 0; e < 32; ++e) {
                unsigned ub = bitsf(g[e]);
                Khi[e*264 + tid] = (short)(ub >> 16);
                float lo = g[e] - fbits(ub & 0xffff0000u);
                Klo[e*264 + tid] = (short)(bitsf(lo) >> 16);
            }
#pragma unroll
            for (int e = 0; e < 32; e += 2)
                ((unsigned*)Vp)[tid*17 + (vslot(e)>>1)] = pkrn(g[e], g[e+1]);
        }
        __syncthreads();
    }

    // ---- epilogue
    const int rbq = bb*LL + q0w;
    if (split) {
#pragma unroll
        for (int mt = 0; mt < 2; ++mt) {
            const int rbase = rbq + 16*mt + 4*quad;
#pragma unroll
            for (int n = 0; n < 16; ++n) {
                const int d = 16*n + il;
#pragma unroll
                for (int b = 0; b < 4; ++b)
                    o_out[(size_t)half*4194304 + (size_t)(rbase + b)*DD + d] = o[mt][n][b];
            }
        }
        if (lane < 16) {
#pragma unroll
            for (int nt = 0; nt < 2; ++nt) {
                int r = rbq + 16*nt + lane;
                *(float2*)(&mlp[((size_t)half*16384 + r)*2]) = make_float2(m_s[nt], l_s[nt]);
            }
        }
    } else {
#pragma unroll
        for (int mt = 0; mt < 2; ++mt) {
            float invl[4];
#pragma unroll
            for (int b = 0; b < 4; ++b) invl[b] = 1.0f / __shfl(l_s[mt], 4*quad + b, 64);
            const int rbase = rbq + 16*mt + 4*quad;
#pragma unroll
            for (int n = 0; n < 16; ++n) {
                const int d = 16*n + il;
#pragma unroll
                for (int b = 0; b < 4; ++b)
                    o_out[(size_t)(rbase + b)*DD + d] = o[mt][n][b] * invl[b];
            }
        }
    }
}

// ---------------- split-K flash combine ----------------
__global__ __launch_bounds__(256)
void combine_kernel(const float* __restrict__ Op, const float* __restrict__ mlp,
                    float* __restrict__ aug)
{
    int t = blockIdx.x*256 + threadIdx.x;      // 16384 * 64 threads
    int r = t >> 6, c = (t & 63) << 2;
    float m0 = mlp[(size_t)r*2],           l0 = mlp[(size_t)r*2 + 1];
    float m1 = mlp[((size_t)16384 + r)*2], l1 = mlp[((size_t)16384 + r)*2 + 1];
    float M  = fmaxf(m0, m1);
    float a0 = __expf(m0 - M), a1 = __expf(m1 - M);
    float inv = 1.0f / (a0*l0 + a1*l1);
    f4_t x0 = *(const f4_t*)(Op + (size_t)r*DD + c);
    f4_t x1 = *(const f4_t*)(Op + 4194304 + (size_t)r*DD + c);
    f4_t res = (x0*a0 + x1*a1) * inv;
    *(f4_t*)(aug + (size_t)r*DD + c) = res;
}

// ---------------- Fusion: out = g*tanh(zWf+bf) + (1-g)*c2 (unchanged, known-good) ----
__global__ __launch_bounds__(256, 2)
void fusion_kernel(const float* __restrict__ c2, const float* __restrict__ aug,
                   const float* __restrict__ Wf, const float* __restrict__ bf,
                   const float* __restrict__ Wg, const float* __restrict__ bg,
                   float* __restrict__ out)
{
    __shared__ float zs[FR][1024];
    __shared__ float gpart[4][FR];
    __shared__ float gv[FR];

    const int tid = threadIdx.x;
    const size_t row0 = (size_t)blockIdx.x * FR;

#pragma unroll
    for (int i = 0; i < 4; ++i) {
        int f = i * 256 + tid;
        int r = f >> 6, d4 = (f & 63) << 2;
        float4 a = *(const float4*)(c2 + (row0 + r) * DD + d4);
        float4 u = *(const float4*)(aug + (row0 + r) * DD + d4);
        *(float4*)(&zs[r][d4]) = a;
        *(float4*)(&zs[r][256 + d4]) = u;
        *(float4*)(&zs[r][512 + d4]) = make_float4(a.x * u.x, a.y * u.y, a.z * u.z, a.w * u.w);
        *(float4*)(&zs[r][768 + d4]) = make_float4(a.x - u.x, a.y - u.y, a.z - u.z, a.w - u.w);
    }
    __syncthreads();

    {
        float4 wg = *(const float4*)(Wg + (tid << 2));
        float gp[FR];
#pragma unroll
        for (int r = 0; r < FR; ++r) {
            float4 z = *(const float4*)(&zs[r][tid << 2]);
            gp[r] = z.x * wg.x + z.y * wg.y + z.z * wg.z + z.w * wg.w;
        }
#pragma unroll
        for (int off = 1; off < 64; off <<= 1) {
#pragma unroll
            for (int r = 0; r < FR; ++r) gp[r] += __shfl_xor(gp[r], off, 64);
        }
        if ((tid & 63) == 0) {
            int w = tid >> 6;
#pragma unroll
            for (int r = 0; r < FR; ++r) gpart[w][r] = gp[r];
        }
    }
    __syncthreads();
    if (tid < FR) {
        float gs = gpart[0][tid] + gpart[1][tid] + gpart[2][tid] + gpart[3][tid] + bg[0];
        gv[tid] = 1.0f / (1.0f + __expf(-gs));
    }
    __syncthreads();

    const int d0  = (tid & 63) << 2;
    const int rr0 = (tid >> 6) << 2;
    float acc[4][4] = {{0.f}};
    for (int k = 0; k < 1024; k += 4) {
        float4 z[4];
#pragma unroll
        for (int i = 0; i < 4; ++i) z[i] = *(const float4*)(&zs[rr0 + i][k]);
#pragma unroll
        for (int kk = 0; kk < 4; ++kk) {
            float4 w = *(const float4*)(Wf + (size_t)(k + kk) * DD + d0);
#pragma unroll
            for (int i = 0; i < 4; ++i) {
                float zz = f4c(z[i], kk);
                acc[i][0] += zz * w.x; acc[i][1] += zz * w.y;
                acc[i][2] += zz * w.z; acc[i][3] += zz * w.w;
            }
        }
    }

    float4 bfv = *(const float4*)(bf + d0);
#pragma unroll
    for (int i = 0; i < 4; ++i) {
        int r = rr0 + i;
        float gg = gv[r];
        float4 cc = *(const float4*)(&zs[r][d0]);
        float4 res;
        res.x = gg * tanhf(acc[i][0] + bfv.x) + (1.f - gg) * cc.x;
        res.y = gg * tanhf(acc[i][1] + bfv.y) + (1.f - gg) * cc.y;
        res.z = gg * tanhf(acc[i][2] + bfv.z) + (1.f - gg) * cc.z;
        res.w = gg * tanhf(acc[i][3] + bfv.w) + (1.f - gg) * cc.w;
        *(float4*)(out + (row0 + r) * DD + d0) = res;
    }
}

extern "C" void kernel_launch(void* const* d_in, const int* in_sizes, int n_in,
                              void* d_out, int out_size, void* d_ws, size_t ws_size,
                              hipStream_t stream)
{
    const float* c1 = (const float*)d_in[0];
    const float* c2 = (const float*)d_in[1];
    const unsigned char* cmask = (const unsigned char*)d_in[2];
    const float* Wf = (const float*)d_in[3];
    const float* bf = (const float*)d_in[4];
    const float* Wg = (const float*)d_in[5];
    const float* bg = (const float*)d_in[6];

    // ws layout (split): Opart[2][16384][256] f32 | ml[2][16384][2] f32 | aug[16384][256] f32
    const size_t opart_elems = (size_t)2 * 16384 * 256;
    const size_t ml_elems    = (size_t)2 * 16384 * 2;
    const size_t need_split  = (opart_elems + ml_elems + (size_t)16384 * 256) * sizeof(float);
    const int split = (ws_size >= need_split) ? 1 : 0;

    float* wsf = (float*)d_ws;
    float *Op, *mlp, *aug;
    if (split) { Op = wsf; mlp = wsf + opart_elems; aug = mlp + ml_elems; }
    else       { Op = wsf; mlp = wsf; aug = wsf; }

    if (split) {
        attn_kernel<<<dim3(256), dim3(256), 0, stream>>>(c1, c2, cmask, Op, mlp, 1024, 1);
        combine_kernel<<<dim3(4096), dim3(256), 0, stream>>>(Op, mlp, aug);
    } else {
        attn_kernel<<<dim3(128), dim3(256), 0, stream>>>(c1, c2, cmask, aug, mlp, 2048, 0);
    }
    fusion_kernel<<<dim3((BB * LL) / FR), dim3(256), 0, stream>>>(c2, aug, Wf, bf, Wg, bg, (float*)d_out);
}

// Round 3
// 340.482 us; speedup vs baseline: 3.0017x; 1.1209x over previous
//
#include <hip/hip_runtime.h>
#include <math.h>

#define BB 8
#define LL 2048
#define DD 256
#define FR 16

typedef float  f4_t __attribute__((ext_vector_type(4)));
typedef short  s8_t __attribute__((ext_vector_type(8)));

union S8U { s8_t v; unsigned u[4]; };

__device__ __forceinline__ unsigned bitsf(float x){ union{float f; unsigned u;} c; c.f=x; return c.u; }
__device__ __forceinline__ float fbits(unsigned u){ union{float f; unsigned u;} c; c.u=u; return c.f; }
// pack two fp32 -> two bf16 (truncate), elem0 in low half
__device__ __forceinline__ unsigned pkhi(float a, float b){ return (bitsf(a)>>16) | (bitsf(b)&0xffff0000u); }
// pack two fp32 -> two bf16 (round-nearest-ish)
__device__ __forceinline__ unsigned pkrn(float a, float b){
    unsigned ua = bitsf(a) + 0x8000u, ub = bitsf(b) + 0x8000u;
    return (ua>>16) | (ub&0xffff0000u);
}
__device__ __forceinline__ float f4c(const float4& v, int i) {
    return i == 0 ? v.x : (i == 1 ? v.y : (i == 2 ? v.z : v.w));
}

// sigma: row e (0..31) of the key tile -> Vperm slot; makes P's MFMA C/D layout
// directly usable as the PV A-operand (slot k=8q+4a+b holds j=16a+4q+b).
__device__ __forceinline__ int vslot(int e){ return ((e>>2)&3)*8 + ((e>>4)<<2) + (e&3); }

// ---------------- MFMA flash attention (unchanged, known-good) ----------------
__global__ __launch_bounds__(256,1)
void attn_kernel(const float* __restrict__ c1, const float* __restrict__ c2,
                 const unsigned char* __restrict__ cmask,
                 float* __restrict__ o_out, float* __restrict__ mlp,
                 int klen, int split)
{
    __shared__ short Khi[32*264];
    __shared__ short Klo[32*264];
    __shared__ short Vp [256*34];

    const int tid  = threadIdx.x;
    const int lane = tid & 63;
    const int w    = tid >> 6;
    const int il   = lane & 15;
    const int quad = lane >> 4;

    const int blk  = blockIdx.x;
    const int bb   = blk & 7;
    const int qb   = (blk >> 3) & 15;
    const int half = split ? (blk >> 7) : 0;
    const int kb   = half * klen;

    const float* c1b = c1 + (size_t)bb * LL * DD;
    const float* c2b = c2 + (size_t)bb * LL * DD;
    const unsigned char* mb = cmask + (size_t)bb * LL;

    const int q0w = qb*128 + w*32;

    s8_t qh[2][8], ql[2][8];
#pragma unroll
    for (int nt = 0; nt < 2; ++nt) {
        const float* qp = c2b + (size_t)(q0w + 16*nt + il)*DD + quad*8;
#pragma unroll
        for (int kd = 0; kd < 8; ++kd) {
            float4 x0 = *(const float4*)(qp + kd*32);
            float4 x1 = *(const float4*)(qp + kd*32 + 4);
            float e[8] = {x0.x,x0.y,x0.z,x0.w,x1.x,x1.y,x1.z,x1.w};
            S8U h, l;
#pragma unroll
            for (int p2 = 0; p2 < 4; ++p2) {
                float a = e[2*p2], b = e[2*p2+1];
                h.u[p2] = pkhi(a, b);
                float alo = a - fbits(bitsf(a)&0xffff0000u);
                float blo = b - fbits(bitsf(b)&0xffff0000u);
                l.u[p2] = pkhi(alo, blo);
            }
            qh[nt][kd] = h.v; ql[nt][kd] = l.v;
        }
    }

    f4_t o[2][16];
#pragma unroll
    for (int mt = 0; mt < 2; ++mt)
#pragma unroll
        for (int n = 0; n < 16; ++n) o[mt][n] = (f4_t)0.0f;
    float m_s[2] = {-INFINITY, -INFINITY};
    float l_s[2] = {0.f, 0.f};

    const int NT = klen >> 5;
    float g[32];

#pragma unroll
    for (int e = 0; e < 32; ++e) g[e] = c1b[(size_t)(kb + e)*DD + tid];
#pragma unroll
    for (int e = 0; e < 32; ++e) {
        unsigned ub = bitsf(g[e]);
        Khi[e*264 + tid] = (short)(ub >> 16);
        float lo = g[e] - fbits(ub & 0xffff0000u);
        Klo[e*264 + tid] = (short)(bitsf(lo) >> 16);
    }
#pragma unroll
    for (int e = 0; e < 32; e += 2)
        ((unsigned*)Vp)[tid*17 + (vslot(e)>>1)] = pkrn(g[e], g[e+1]);
    __syncthreads();

    for (int kt = 0; kt < NT; ++kt) {
        const int k0 = kt << 5;
        if (kt + 1 < NT) {
#pragma unroll
            for (int e = 0; e < 32; ++e) g[e] = c1b[(size_t)(kb + k0 + 32 + e)*DD + tid];
        }

        f4_t acc[2][2];
#pragma unroll
        for (int mj = 0; mj < 2; ++mj)
#pragma unroll
            for (int nt = 0; nt < 2; ++nt) acc[mj][nt] = (f4_t)0.0f;

#pragma unroll
        for (int kd = 0; kd < 8; ++kd) {
            s8_t ah0 = *(const s8_t*)&Khi[(il     )*264 + kd*32 + quad*8];
            s8_t ah1 = *(const s8_t*)&Khi[(16 + il)*264 + kd*32 + quad*8];
            s8_t al0 = *(const s8_t*)&Klo[(il     )*264 + kd*32 + quad*8];
            s8_t al1 = *(const s8_t*)&Klo[(16 + il)*264 + kd*32 + quad*8];
#pragma unroll
            for (int nt = 0; nt < 2; ++nt) {
                acc[0][nt] = __builtin_amdgcn_mfma_f32_16x16x32_bf16(ah0, qh[nt][kd], acc[0][nt], 0,0,0);
                acc[1][nt] = __builtin_amdgcn_mfma_f32_16x16x32_bf16(ah1, qh[nt][kd], acc[1][nt], 0,0,0);
                acc[0][nt] = __builtin_amdgcn_mfma_f32_16x16x32_bf16(al0, qh[nt][kd], acc[0][nt], 0,0,0);
                acc[1][nt] = __builtin_amdgcn_mfma_f32_16x16x32_bf16(al1, qh[nt][kd], acc[1][nt], 0,0,0);
                acc[0][nt] = __builtin_amdgcn_mfma_f32_16x16x32_bf16(ah0, ql[nt][kd], acc[0][nt], 0,0,0);
                acc[1][nt] = __builtin_amdgcn_mfma_f32_16x16x32_bf16(ah1, ql[nt][kd], acc[1][nt], 0,0,0);
            }
        }

        unsigned mu[2];
#pragma unroll
        for (int mj = 0; mj < 2; ++mj)
            mu[mj] = *(const unsigned*)(mb + kb + k0 + 16*mj + 4*quad);

        f4_t p[2][2];
        float alpha_v[2];
#pragma unroll
        for (int nt = 0; nt < 2; ++nt) {
            const int ig = q0w + 16*nt + il;
            float mn = m_s[nt];
#pragma unroll
            for (int mj = 0; mj < 2; ++mj) {
#pragma unroll
                for (int b = 0; b < 4; ++b) {
                    int jg = kb + k0 + 16*mj + 4*quad + b;
                    float s = acc[mj][nt][b];
                    bool dead = (((mu[mj] >> (8*b)) & 0xff) != 0) || (jg == ig);
                    s = dead ? -INFINITY : s;
                    p[mj][nt][b] = s;
                    mn = fmaxf(mn, s);
                }
            }
            mn = fmaxf(mn, __shfl_xor(mn, 16, 64));
            mn = fmaxf(mn, __shfl_xor(mn, 32, 64));
            float al = __expf(m_s[nt] - mn);
            float rs = 0.f;
#pragma unroll
            for (int mj = 0; mj < 2; ++mj) {
#pragma unroll
                for (int b = 0; b < 4; ++b) {
                    float pe = __expf(p[mj][nt][b] - mn);
                    p[mj][nt][b] = pe;
                    rs += pe;
                }
            }
            rs += __shfl_xor(rs, 16, 64);
            rs += __shfl_xor(rs, 32, 64);
            l_s[nt] = l_s[nt]*al + rs;
            m_s[nt] = mn;
            alpha_v[nt] = al;
        }

#pragma unroll
        for (int mt = 0; mt < 2; ++mt) {
            float am[4];
#pragma unroll
            for (int b = 0; b < 4; ++b) am[b] = __shfl(alpha_v[mt], 4*quad + b, 64);
#pragma unroll
            for (int n = 0; n < 16; ++n) {
#pragma unroll
                for (int b = 0; b < 4; ++b) o[mt][n][b] *= am[b];
            }
        }

        s8_t ap[2];
#pragma unroll
        for (int mt = 0; mt < 2; ++mt) {
            S8U a;
            a.u[0] = pkrn(p[0][mt][0], p[0][mt][1]);
            a.u[1] = pkrn(p[0][mt][2], p[0][mt][3]);
            a.u[2] = pkrn(p[1][mt][0], p[1][mt][1]);
            a.u[3] = pkrn(p[1][mt][2], p[1][mt][3]);
            ap[mt] = a.v;
        }
#pragma unroll
        for (int n = 0; n < 16; ++n) {
            S8U bv;
#pragma unroll
            for (int dd = 0; dd < 4; ++dd)
                bv.u[dd] = ((const unsigned*)Vp)[(16*n + il)*17 + quad*4 + dd];
            o[0][n] = __builtin_amdgcn_mfma_f32_16x16x32_bf16(ap[0], bv.v, o[0][n], 0,0,0);
            o[1][n] = __builtin_amdgcn_mfma_f32_16x16x32_bf16(ap[1], bv.v, o[1][n], 0,0,0);
        }

        __syncthreads();
        if (kt + 1 < NT) {
#pragma unroll
            for (int e = 0; e < 32; ++e) {
                unsigned ub = bitsf(g[e]);
                Khi[e*264 + tid] = (short)(ub >> 16);
                float lo = g[e] - fbits(ub & 0xffff0000u);
                Klo[e*264 + tid] = (short)(bitsf(lo) >> 16);
            }
#pragma unroll
            for (int e = 0; e < 32; e += 2)
                ((unsigned*)Vp)[tid*17 + (vslot(e)>>1)] = pkrn(g[e], g[e+1]);
        }
        __syncthreads();
    }

    const int rbq = bb*LL + q0w;
    if (split) {
#pragma unroll
        for (int mt = 0; mt < 2; ++mt) {
            const int rbase = rbq + 16*mt + 4*quad;
#pragma unroll
            for (int n = 0; n < 16; ++n) {
                const int d = 16*n + il;
#pragma unroll
                for (int b = 0; b < 4; ++b)
                    o_out[(size_t)half*4194304 + (size_t)(rbase + b)*DD + d] = o[mt][n][b];
            }
        }
        if (lane < 16) {
#pragma unroll
            for (int nt = 0; nt < 2; ++nt) {
                int r = rbq + 16*nt + lane;
                *(float2*)(&mlp[((size_t)half*16384 + r)*2]) = make_float2(m_s[nt], l_s[nt]);
            }
        }
    } else {
#pragma unroll
        for (int mt = 0; mt < 2; ++mt) {
            float invl[4];
#pragma unroll
            for (int b = 0; b < 4; ++b) invl[b] = 1.0f / __shfl(l_s[mt], 4*quad + b, 64);
            const int rbase = rbq + 16*mt + 4*quad;
#pragma unroll
            for (int n = 0; n < 16; ++n) {
                const int d = 16*n + il;
#pragma unroll
                for (int b = 0; b < 4; ++b)
                    o_out[(size_t)(rbase + b)*DD + d] = o[mt][n][b] * invl[b];
            }
        }
    }
}

// ---------------- split-K flash combine ----------------
__global__ __launch_bounds__(256)
void combine_kernel(const float* __restrict__ Op, const float* __restrict__ mlp,
                    float* __restrict__ aug)
{
    int t = blockIdx.x*256 + threadIdx.x;
    int r = t >> 6, c = (t & 63) << 2;
    float m0 = mlp[(size_t)r*2],           l0 = mlp[(size_t)r*2 + 1];
    float m1 = mlp[((size_t)16384 + r)*2], l1 = mlp[((size_t)16384 + r)*2 + 1];
    float M  = fmaxf(m0, m1);
    float a0 = __expf(m0 - M), a1 = __expf(m1 - M);
    float inv = 1.0f / (a0*l0 + a1*l1);
    f4_t x0 = *(const f4_t*)(Op + (size_t)r*DD + c);
    f4_t x1 = *(const f4_t*)(Op + 4194304 + (size_t)r*DD + c);
    f4_t res = (x0*a0 + x1*a1) * inv;
    *(f4_t*)(aug + (size_t)r*DD + c) = res;
}

// ---------------- prep: W' = [W1+W4; W2-W4; W3] -> bf16 hi/lo in MFMA B-frag order ----
// frag uint index: (((kc*3+seg)*16+nt)*64+lane)*4+p ; holds W'[seg*256+kc*32+(lane>>4)*8+2p (+1)][nt*16+(lane&15)]
__global__ __launch_bounds__(256)
void prep_kernel(const float* __restrict__ Wf, const float* __restrict__ Wg,
                 unsigned* __restrict__ Whi, unsigned* __restrict__ Wlo,
                 float* __restrict__ gw)
{
    if (blockIdx.x == 384) {
#pragma unroll
        for (int i = 0; i < 3; ++i) {
            int kl = threadIdx.x;
            float v = (i == 0) ? (Wg[kl] + Wg[768 + kl])
                    : (i == 1) ? (Wg[256 + kl] - Wg[768 + kl])
                               :  Wg[512 + kl];
            gw[i*256 + kl] = v;
        }
        return;
    }
    int t    = blockIdx.x*256 + threadIdx.x;    // [0, 98304)
    int p    = t & 3;
    int lane = (t >> 2) & 63;
    int nt   = (t >> 8) & 15;
    int g2   = t >> 12;                          // kc*3 + seg, [0,24)
    int seg  = g2 % 3;
    int kc   = g2 / 3;
    int kl   = kc*32 + (lane >> 4)*8 + 2*p;
    int n    = nt*16 + (lane & 15);
    float v0, v1;
    if (seg == 0) {
        v0 = Wf[(size_t)kl*DD + n]       + Wf[(size_t)(768 + kl)*DD + n];
        v1 = Wf[(size_t)(kl + 1)*DD + n] + Wf[(size_t)(769 + kl)*DD + n];
    } else if (seg == 1) {
        v0 = Wf[(size_t)(256 + kl)*DD + n] - Wf[(size_t)(768 + kl)*DD + n];
        v1 = Wf[(size_t)(257 + kl)*DD + n] - Wf[(size_t)(769 + kl)*DD + n];
    } else {
        v0 = Wf[(size_t)(512 + kl)*DD + n];
        v1 = Wf[(size_t)(513 + kl)*DD + n];
    }
    Whi[t] = pkhi(v0, v1);
    float l0 = v0 - fbits(bitsf(v0) & 0xffff0000u);
    float l1 = v1 - fbits(bitsf(v1) & 0xffff0000u);
    Wlo[t] = pkrn(l0, l1);
}

// ---------------- MFMA fusion: out = g*tanh(zW'+bf) + (1-g)*c2 ----------------
// block = 64 rows; wave w covers cols [64w, 64w+64). 2 passes: z_rn*Whi + z_rn*Wlo.
__global__ __launch_bounds__(256,1)
void fusion_mfma(const float* __restrict__ c2, const float* __restrict__ aug,
                 const unsigned* __restrict__ Whi, const unsigned* __restrict__ Wlo,
                 const float* __restrict__ gw, const float* __restrict__ bg,
                 const float* __restrict__ bf, float* __restrict__ out)
{
    __shared__ float gpart[256];
    __shared__ float gv[64];

    const int tid  = threadIdx.x;
    const int lane = tid & 63;
    const int w    = tid >> 6;
    const int il   = lane & 15;
    const int quad = lane >> 4;
    const size_t row0 = (size_t)blockIdx.x * 64;

    const float* c2b  = c2 + row0*DD;
    const float* augb = aug + row0*DD;

    // ---- gate: thread (r = tid&63, qq = tid>>6) covers k in [qq*192, qq*192+192)
    {
        const int r = tid & 63, qq = tid >> 6;
        const float* c2r  = c2b + (size_t)r*DD;
        const float* augr = augb + (size_t)r*DD;
        float s = 0.f;
#pragma unroll 4
        for (int k = qq*192; k < qq*192 + 192; ++k) {
            int seg = k >> 8, c = k & 255;
            float x = (seg == 0) ? c2r[c] : (seg == 1) ? augr[c] : c2r[c]*augr[c];
            s += x * gw[k];
        }
        gpart[tid] = s;
    }
    __syncthreads();
    if (tid < 64) {
        float gs = gpart[tid] + gpart[64 + tid] + gpart[128 + tid] + gpart[192 + tid] + bg[0];
        gv[tid] = 1.0f / (1.0f + __expf(-gs));
    }
    __syncthreads();

    // ---- GEMM: acc[mt][nt] = z[row 16mt+..][k] * W'[k][col 64w+16nt+..]
    f4_t acc[4][4];
#pragma unroll
    for (int mt = 0; mt < 4; ++mt)
#pragma unroll
        for (int nt = 0; nt < 4; ++nt) acc[mt][nt] = (f4_t)0.0f;

    for (int kc = 0; kc < 8; ++kc) {
        s8_t za[4], zb[4], zc[4];
#pragma unroll
        for (int mt = 0; mt < 4; ++mt) {
            const float* pr = c2b  + (size_t)(16*mt + il)*DD + kc*32 + quad*8;
            const float* pu = augb + (size_t)(16*mt + il)*DD + kc*32 + quad*8;
            float4 a0 = *(const float4*)pr, a1 = *(const float4*)(pr + 4);
            float4 u0 = *(const float4*)pu, u1 = *(const float4*)(pu + 4);
            float ea[8] = {a0.x,a0.y,a0.z,a0.w,a1.x,a1.y,a1.z,a1.w};
            float eu[8] = {u0.x,u0.y,u0.z,u0.w,u1.x,u1.y,u1.z,u1.w};
            S8U A, U, Pd;
#pragma unroll
            for (int p = 0; p < 4; ++p) {
                A.u[p]  = pkrn(ea[2*p], ea[2*p+1]);
                U.u[p]  = pkrn(eu[2*p], eu[2*p+1]);
                Pd.u[p] = pkrn(ea[2*p]*eu[2*p], ea[2*p+1]*eu[2*p+1]);
            }
            za[mt] = A.v; zb[mt] = U.v; zc[mt] = Pd.v;
        }
#pragma unroll
        for (int nt = 0; nt < 4; ++nt) {
            const int ntg = w*4 + nt;
            const size_t f0 = ((size_t)((kc*3 + 0)*16 + ntg)*64 + lane)*4;
            const size_t f1 = ((size_t)((kc*3 + 1)*16 + ntg)*64 + lane)*4;
            const size_t f2 = ((size_t)((kc*3 + 2)*16 + ntg)*64 + lane)*4;
            s8_t w0h = *(const s8_t*)(Whi + f0), w0l = *(const s8_t*)(Wlo + f0);
            s8_t w1h = *(const s8_t*)(Whi + f1), w1l = *(const s8_t*)(Wlo + f1);
            s8_t w2h = *(const s8_t*)(Whi + f2), w2l = *(const s8_t*)(Wlo + f2);
#pragma unroll
            for (int mt = 0; mt < 4; ++mt) {
                acc[mt][nt] = __builtin_amdgcn_mfma_f32_16x16x32_bf16(za[mt], w0h, acc[mt][nt], 0,0,0);
                acc[mt][nt] = __builtin_amdgcn_mfma_f32_16x16x32_bf16(za[mt], w0l, acc[mt][nt], 0,0,0);
                acc[mt][nt] = __builtin_amdgcn_mfma_f32_16x16x32_bf16(zb[mt], w1h, acc[mt][nt], 0,0,0);
                acc[mt][nt] = __builtin_amdgcn_mfma_f32_16x16x32_bf16(zb[mt], w1l, acc[mt][nt], 0,0,0);
                acc[mt][nt] = __builtin_amdgcn_mfma_f32_16x16x32_bf16(zc[mt], w2h, acc[mt][nt], 0,0,0);
                acc[mt][nt] = __builtin_amdgcn_mfma_f32_16x16x32_bf16(zc[mt], w2l, acc[mt][nt], 0,0,0);
            }
        }
    }

    // ---- epilogue: row = 16mt + 4*quad + b, col = 64w + 16nt + il
#pragma unroll
    for (int nt = 0; nt < 4; ++nt) {
        const int col = w*64 + nt*16 + il;
        const float bfv = bf[col];
#pragma unroll
        for (int mt = 0; mt < 4; ++mt) {
#pragma unroll
            for (int b = 0; b < 4; ++b) {
                const int r = 16*mt + 4*quad + b;
                const float g = gv[r];
                const float cc = c2b[(size_t)r*DD + col];
                out[(row0 + r)*DD + col] = g * tanhf(acc[mt][nt][b] + bfv) + (1.f - g) * cc;
            }
        }
    }
}

extern "C" void kernel_launch(void* const* d_in, const int* in_sizes, int n_in,
                              void* d_out, int out_size, void* d_ws, size_t ws_size,
                              hipStream_t stream)
{
    const float* c1 = (const float*)d_in[0];
    const float* c2 = (const float*)d_in[1];
    const unsigned char* cmask = (const unsigned char*)d_in[2];
    const float* Wf = (const float*)d_in[3];
    const float* bf = (const float*)d_in[4];
    const float* Wg = (const float*)d_in[5];
    const float* bg = (const float*)d_in[6];

    // ws layout (split): Op[2*16384*256] | mlp[2*16384*2] | aug[16384*256]
    // Wfrag (Whi/Wlo/gw) ALIASES Op: prep runs after combine, when Op is dead.
    const size_t opart_elems = (size_t)2 * 16384 * 256;
    const size_t ml_elems    = (size_t)2 * 16384 * 2;
    const size_t aug_elems   = (size_t)16384 * 256;
    const size_t frag_elems  = (size_t)98304;   // uints per buffer
    const size_t need_split  = (opart_elems + ml_elems + aug_elems) * sizeof(float);
    const size_t need_nosplit= (aug_elems + 2*frag_elems + 768) * sizeof(float);
    const int split = (ws_size >= need_split) ? 1 : 0;

    float* wsf = (float*)d_ws;
    float *Op, *mlp, *aug;
    unsigned *Whi, *Wlo; float *gw;
    if (split) {
        Op  = wsf; mlp = wsf + opart_elems; aug = mlp + ml_elems;
        Whi = (unsigned*)Op; Wlo = Whi + frag_elems; gw = (float*)(Wlo + frag_elems);
    } else {
        Op  = wsf; mlp = wsf; aug = wsf;
        Whi = (unsigned*)(wsf + aug_elems); Wlo = Whi + frag_elems; gw = (float*)(Wlo + frag_elems);
    }

    if (split) {
        attn_kernel<<<dim3(256), dim3(256), 0, stream>>>(c1, c2, cmask, Op, mlp, 1024, 1);
        combine_kernel<<<dim3(4096), dim3(256), 0, stream>>>(Op, mlp, aug);
        prep_kernel<<<dim3(385), dim3(256), 0, stream>>>(Wf, Wg, Whi, Wlo, gw);
        fusion_mfma<<<dim3(256), dim3(256), 0, stream>>>(c2, aug, Whi, Wlo, gw, bg, bf, (float*)d_out);
    } else if (ws_size >= need_nosplit) {
        attn_kernel<<<dim3(128), dim3(256), 0, stream>>>(c1, c2, cmask, aug, mlp, 2048, 0);
        prep_kernel<<<dim3(385), dim3(256), 0, stream>>>(Wf, Wg, Whi, Wlo, gw);
        fusion_mfma<<<dim3(256), dim3(256), 0, stream>>>(c2, aug, Whi, Wlo, gw, bg, bf, (float*)d_out);
    } else {
        // minimal fallback: no-split attn directly to aug, VALU fusion not kept -> still MFMA path
        attn_kernel<<<dim3(128), dim3(256), 0, stream>>>(c1, c2, cmask, aug, mlp, 2048, 0);
        prep_kernel<<<dim3(385), dim3(256), 0, stream>>>(Wf, Wg, Whi, Wlo, gw);
        fusion_mfma<<<dim3(256), dim3(256), 0, stream>>>(c2, aug, Whi, Wlo, gw, bg, bf, (float*)d_out);
    }
}

// Round 7
// 303.684 us; speedup vs baseline: 3.3654x; 1.1212x over previous
//
#include <hip/hip_runtime.h>
#include <math.h>

#define BB 8
#define LL 2048
#define DD 256

typedef float  f4_t __attribute__((ext_vector_type(4)));
typedef short  s8_t __attribute__((ext_vector_type(8)));

union S8U { s8_t v; unsigned u[4]; };

__device__ __forceinline__ unsigned bitsf(float x){ union{float f; unsigned u;} c; c.f=x; return c.u; }
__device__ __forceinline__ float fbits(unsigned u){ union{float f; unsigned u;} c; c.u=u; return c.f; }
// pack two fp32 -> two bf16 (truncate), elem0 in low half
__device__ __forceinline__ unsigned pkhi(float a, float b){ return (bitsf(a)>>16) | (bitsf(b)&0xffff0000u); }
// pack two fp32 -> two bf16 (round-nearest-ish)
__device__ __forceinline__ unsigned pkrn(float a, float b){
    unsigned ua = bitsf(a) + 0x8000u, ub = bitsf(b) + 0x8000u;
    return (ua>>16) | (ub&0xffff0000u);
}

// sigma: row e (0..31) of the key tile -> Vperm slot; makes P's MFMA C/D layout
// directly usable as the PV A-operand (slot k=8q+4a+b holds j=16a+4q+b).
__device__ __forceinline__ int vslot(int e){ return ((e>>2)&3)*8 + ((e>>4)<<2) + (e&3); }

// ---------------- MFMA flash attention (EXACT R3 version — known-good) ----------------
__global__ __launch_bounds__(256,1)
void attn_kernel(const float* __restrict__ c1, const float* __restrict__ c2,
                 const unsigned char* __restrict__ cmask,
                 float* __restrict__ o_out, float* __restrict__ mlp,
                 int klen, int split)
{
    __shared__ short Khi[32*264];
    __shared__ short Klo[32*264];
    __shared__ short Vp [256*34];

    const int tid  = threadIdx.x;
    const int lane = tid & 63;
    const int w    = tid >> 6;
    const int il   = lane & 15;
    const int quad = lane >> 4;

    const int blk  = blockIdx.x;
    const int bb   = blk & 7;
    const int qb   = (blk >> 3) & 15;
    const int half = split ? (blk >> 7) : 0;
    const int kb   = half * klen;

    const float* c1b = c1 + (size_t)bb * LL * DD;
    const float* c2b = c2 + (size_t)bb * LL * DD;
    const unsigned char* mb = cmask + (size_t)bb * LL;

    const int q0w = qb*128 + w*32;

    s8_t qh[2][8], ql[2][8];
#pragma unroll
    for (int nt = 0; nt < 2; ++nt) {
        const float* qp = c2b + (size_t)(q0w + 16*nt + il)*DD + quad*8;
#pragma unroll
        for (int kd = 0; kd < 8; ++kd) {
            float4 x0 = *(const float4*)(qp + kd*32);
            float4 x1 = *(const float4*)(qp + kd*32 + 4);
            float e[8] = {x0.x,x0.y,x0.z,x0.w,x1.x,x1.y,x1.z,x1.w};
            S8U h, l;
#pragma unroll
            for (int p2 = 0; p2 < 4; ++p2) {
                float a = e[2*p2], b = e[2*p2+1];
                h.u[p2] = pkhi(a, b);
                float alo = a - fbits(bitsf(a)&0xffff0000u);
                float blo = b - fbits(bitsf(b)&0xffff0000u);
                l.u[p2] = pkhi(alo, blo);
            }
            qh[nt][kd] = h.v; ql[nt][kd] = l.v;
        }
    }

    f4_t o[2][16];
#pragma unroll
    for (int mt = 0; mt < 2; ++mt)
#pragma unroll
        for (int n = 0; n < 16; ++n) o[mt][n] = (f4_t)0.0f;
    float m_s[2] = {-INFINITY, -INFINITY};
    float l_s[2] = {0.f, 0.f};

    const int NT = klen >> 5;
    float g[32];

#pragma unroll
    for (int e = 0; e < 32; ++e) g[e] = c1b[(size_t)(kb + e)*DD + tid];
#pragma unroll
    for (int e = 0; e < 32; ++e) {
        unsigned ub = bitsf(g[e]);
        Khi[e*264 + tid] = (short)(ub >> 16);
        float lo = g[e] - fbits(ub & 0xffff0000u);
        Klo[e*264 + tid] = (short)(bitsf(lo) >> 16);
    }
#pragma unroll
    for (int e = 0; e < 32; e += 2)
        ((unsigned*)Vp)[tid*17 + (vslot(e)>>1)] = pkrn(g[e], g[e+1]);
    __syncthreads();

    for (int kt = 0; kt < NT; ++kt) {
        const int k0 = kt << 5;
        if (kt + 1 < NT) {
#pragma unroll
            for (int e = 0; e < 32; ++e) g[e] = c1b[(size_t)(kb + k0 + 32 + e)*DD + tid];
        }

        f4_t acc[2][2];
#pragma unroll
        for (int mj = 0; mj < 2; ++mj)
#pragma unroll
            for (int nt = 0; nt < 2; ++nt) acc[mj][nt] = (f4_t)0.0f;

#pragma unroll
        for (int kd = 0; kd < 8; ++kd) {
            s8_t ah0 = *(const s8_t*)&Khi[(il     )*264 + kd*32 + quad*8];
            s8_t ah1 = *(const s8_t*)&Khi[(16 + il)*264 + kd*32 + quad*8];
            s8_t al0 = *(const s8_t*)&Klo[(il     )*264 + kd*32 + quad*8];
            s8_t al1 = *(const s8_t*)&Klo[(16 + il)*264 + kd*32 + quad*8];
#pragma unroll
            for (int nt = 0; nt < 2; ++nt) {
                acc[0][nt] = __builtin_amdgcn_mfma_f32_16x16x32_bf16(ah0, qh[nt][kd], acc[0][nt], 0,0,0);
                acc[1][nt] = __builtin_amdgcn_mfma_f32_16x16x32_bf16(ah1, qh[nt][kd], acc[1][nt], 0,0,0);
                acc[0][nt] = __builtin_amdgcn_mfma_f32_16x16x32_bf16(al0, qh[nt][kd], acc[0][nt], 0,0,0);
                acc[1][nt] = __builtin_amdgcn_mfma_f32_16x16x32_bf16(al1, qh[nt][kd], acc[1][nt], 0,0,0);
                acc[0][nt] = __builtin_amdgcn_mfma_f32_16x16x32_bf16(ah0, ql[nt][kd], acc[0][nt], 0,0,0);
                acc[1][nt] = __builtin_amdgcn_mfma_f32_16x16x32_bf16(ah1, ql[nt][kd], acc[1][nt], 0,0,0);
            }
        }

        unsigned mu[2];
#pragma unroll
        for (int mj = 0; mj < 2; ++mj)
            mu[mj] = *(const unsigned*)(mb + kb + k0 + 16*mj + 4*quad);

        f4_t p[2][2];
        float alpha_v[2];
#pragma unroll
        for (int nt = 0; nt < 2; ++nt) {
            const int ig = q0w + 16*nt + il;
            float mn = m_s[nt];
#pragma unroll
            for (int mj = 0; mj < 2; ++mj) {
#pragma unroll
                for (int b = 0; b < 4; ++b) {
                    int jg = kb + k0 + 16*mj + 4*quad + b;
                    float s = acc[mj][nt][b];
                    bool dead = (((mu[mj] >> (8*b)) & 0xff) != 0) || (jg == ig);
                    s = dead ? -INFINITY : s;
                    p[mj][nt][b] = s;
                    mn = fmaxf(mn, s);
                }
            }
            mn = fmaxf(mn, __shfl_xor(mn, 16, 64));
            mn = fmaxf(mn, __shfl_xor(mn, 32, 64));
            float al = __expf(m_s[nt] - mn);
            float rs = 0.f;
#pragma unroll
            for (int mj = 0; mj < 2; ++mj) {
#pragma unroll
                for (int b = 0; b < 4; ++b) {
                    float pe = __expf(p[mj][nt][b] - mn);
                    p[mj][nt][b] = pe;
                    rs += pe;
                }
            }
            rs += __shfl_xor(rs, 16, 64);
            rs += __shfl_xor(rs, 32, 64);
            l_s[nt] = l_s[nt]*al + rs;
            m_s[nt] = mn;
            alpha_v[nt] = al;
        }

#pragma unroll
        for (int mt = 0; mt < 2; ++mt) {
            float am[4];
#pragma unroll
            for (int b = 0; b < 4; ++b) am[b] = __shfl(alpha_v[mt], 4*quad + b, 64);
#pragma unroll
            for (int n = 0; n < 16; ++n) {
#pragma unroll
                for (int b = 0; b < 4; ++b) o[mt][n][b] *= am[b];
            }
        }

        s8_t ap[2];
#pragma unroll
        for (int mt = 0; mt < 2; ++mt) {
            S8U a;
            a.u[0] = pkrn(p[0][mt][0], p[0][mt][1]);
            a.u[1] = pkrn(p[0][mt][2], p[0][mt][3]);
            a.u[2] = pkrn(p[1][mt][0], p[1][mt][1]);
            a.u[3] = pkrn(p[1][mt][2], p[1][mt][3]);
            ap[mt] = a.v;
        }
#pragma unroll
        for (int n = 0; n < 16; ++n) {
            S8U bv;
#pragma unroll
            for (int dd = 0; dd < 4; ++dd)
                bv.u[dd] = ((const unsigned*)Vp)[(16*n + il)*17 + quad*4 + dd];
            o[0][n] = __builtin_amdgcn_mfma_f32_16x16x32_bf16(ap[0], bv.v, o[0][n], 0,0,0);
            o[1][n] = __builtin_amdgcn_mfma_f32_16x16x32_bf16(ap[1], bv.v, o[1][n], 0,0,0);
        }

        __syncthreads();
        if (kt + 1 < NT) {
#pragma unroll
            for (int e = 0; e < 32; ++e) {
                unsigned ub = bitsf(g[e]);
                Khi[e*264 + tid] = (short)(ub >> 16);
                float lo = g[e] - fbits(ub & 0xffff0000u);
                Klo[e*264 + tid] = (short)(bitsf(lo) >> 16);
            }
#pragma unroll
            for (int e = 0; e < 32; e += 2)
                ((unsigned*)Vp)[tid*17 + (vslot(e)>>1)] = pkrn(g[e], g[e+1]);
        }
        __syncthreads();
    }

    const int rbq = bb*LL + q0w;
    if (split) {
#pragma unroll
        for (int mt = 0; mt < 2; ++mt) {
            const int rbase = rbq + 16*mt + 4*quad;
#pragma unroll
            for (int n = 0; n < 16; ++n) {
                const int d = 16*n + il;
#pragma unroll
                for (int b = 0; b < 4; ++b)
                    o_out[(size_t)half*4194304 + (size_t)(rbase + b)*DD + d] = o[mt][n][b];
            }
        }
        if (lane < 16) {
#pragma unroll
            for (int nt = 0; nt < 2; ++nt) {
                int r = rbq + 16*nt + lane;
                *(float2*)(&mlp[((size_t)half*16384 + r)*2]) = make_float2(m_s[nt], l_s[nt]);
            }
        }
    } else {
#pragma unroll
        for (int mt = 0; mt < 2; ++mt) {
            float invl[4];
#pragma unroll
            for (int b = 0; b < 4; ++b) invl[b] = 1.0f / __shfl(l_s[mt], 4*quad + b, 64);
            const int rbase = rbq + 16*mt + 4*quad;
#pragma unroll
            for (int n = 0; n < 16; ++n) {
                const int d = 16*n + il;
#pragma unroll
                for (int b = 0; b < 4; ++b)
                    o_out[(size_t)(rbase + b)*DD + d] = o[mt][n][b] * invl[b];
            }
        }
    }
}

// ---------------- split-K flash combine (EXACT R3 version) ----------------
__global__ __launch_bounds__(256)
void combine_kernel(const float* __restrict__ Op, const float* __restrict__ mlp,
                    float* __restrict__ aug)
{
    int t = blockIdx.x*256 + threadIdx.x;
    int r = t >> 6, c = (t & 63) << 2;
    float m0 = mlp[(size_t)r*2],           l0 = mlp[(size_t)r*2 + 1];
    float m1 = mlp[((size_t)16384 + r)*2], l1 = mlp[((size_t)16384 + r)*2 + 1];
    float M  = fmaxf(m0, m1);
    float a0 = __expf(m0 - M), a1 = __expf(m1 - M);
    float inv = 1.0f / (a0*l0 + a1*l1);
    f4_t x0 = *(const f4_t*)(Op + (size_t)r*DD + c);
    f4_t x1 = *(const f4_t*)(Op + 4194304 + (size_t)r*DD + c);
    f4_t res = (x0*a0 + x1*a1) * inv;
    *(f4_t*)(aug + (size_t)r*DD + c) = res;
}

// ---------------- prep (EXACT R3 version) ----------------
__global__ __launch_bounds__(256)
void prep_kernel(const float* __restrict__ Wf, const float* __restrict__ Wg,
                 unsigned* __restrict__ Whi, unsigned* __restrict__ Wlo,
                 float* __restrict__ gw)
{
    if (blockIdx.x == 384) {
#pragma unroll
        for (int i = 0; i < 3; ++i) {
            int kl = threadIdx.x;
            float v = (i == 0) ? (Wg[kl] + Wg[768 + kl])
                    : (i == 1) ? (Wg[256 + kl] - Wg[768 + kl])
                               :  Wg[512 + kl];
            gw[i*256 + kl] = v;
        }
        return;
    }
    int t    = blockIdx.x*256 + threadIdx.x;    // [0, 98304)
    int p    = t & 3;
    int lane = (t >> 2) & 63;
    int nt   = (t >> 8) & 15;
    int g2   = t >> 12;                          // kc*3 + seg, [0,24)
    int seg  = g2 % 3;
    int kc   = g2 / 3;
    int kl   = kc*32 + (lane >> 4)*8 + 2*p;
    int n    = nt*16 + (lane & 15);
    float v0, v1;
    if (seg == 0) {
        v0 = Wf[(size_t)kl*DD + n]       + Wf[(size_t)(768 + kl)*DD + n];
        v1 = Wf[(size_t)(kl + 1)*DD + n] + Wf[(size_t)(769 + kl)*DD + n];
    } else if (seg == 1) {
        v0 = Wf[(size_t)(256 + kl)*DD + n] - Wf[(size_t)(768 + kl)*DD + n];
        v1 = Wf[(size_t)(257 + kl)*DD + n] - Wf[(size_t)(769 + kl)*DD + n];
    } else {
        v0 = Wf[(size_t)(512 + kl)*DD + n];
        v1 = Wf[(size_t)(513 + kl)*DD + n];
    }
    Whi[t] = pkhi(v0, v1);
    float l0 = v0 - fbits(bitsf(v0) & 0xffff0000u);
    float l1 = v1 - fbits(bitsf(v1) & 0xffff0000u);
    Wlo[t] = pkrn(l0, l1);
}

// ---------------- MFMA fusion: R3 64-row version, ONLY the gate changed ----------------
// Gate accumulated from the same fp32 ea/eu fragment values (gw staged in LDS).
// gv written by wave 0 only (every lane holds the full sum after the shfl reduce).
__global__ __launch_bounds__(256,1)
void fusion_mfma(const float* __restrict__ c2, const float* __restrict__ aug,
                 const unsigned* __restrict__ Whi, const unsigned* __restrict__ Wlo,
                 const float* __restrict__ gw, const float* __restrict__ bg,
                 const float* __restrict__ bf, float* __restrict__ out)
{
    __shared__ float gwL[768];
    __shared__ float gv[64];

    const int tid  = threadIdx.x;
    const int lane = tid & 63;
    const int w    = tid >> 6;
    const int il   = lane & 15;
    const int quad = lane >> 4;
    const size_t row0 = (size_t)blockIdx.x * 64;

    const float* c2b  = c2 + row0*DD;
    const float* augb = aug + row0*DD;

    // stage gw -> LDS (broadcast reads later)
    for (int i = tid; i < 768; i += 256) gwL[i] = gw[i];
    __syncthreads();

    f4_t acc[4][4];
#pragma unroll
    for (int mt = 0; mt < 4; ++mt)
#pragma unroll
        for (int nt = 0; nt < 4; ++nt) acc[mt][nt] = (f4_t)0.0f;
    float gp[4] = {0.f, 0.f, 0.f, 0.f};

    for (int kc = 0; kc < 8; ++kc) {
        s8_t za[4], zb[4], zc[4];
        const int c0 = kc*32 + quad*8;
#pragma unroll
        for (int mt = 0; mt < 4; ++mt) {
            const float* pr = c2b  + (size_t)(16*mt + il)*DD + c0;
            const float* pu = augb + (size_t)(16*mt + il)*DD + c0;
            float4 a0 = *(const float4*)pr, a1 = *(const float4*)(pr + 4);
            float4 u0 = *(const float4*)pu, u1 = *(const float4*)(pu + 4);
            float ea[8] = {a0.x,a0.y,a0.z,a0.w,a1.x,a1.y,a1.z,a1.w};
            float eu[8] = {u0.x,u0.y,u0.z,u0.w,u1.x,u1.y,u1.z,u1.w};
#pragma unroll
            for (int j = 0; j < 8; ++j)
                gp[mt] += ea[j]*gwL[c0+j] + eu[j]*gwL[256+c0+j] + (ea[j]*eu[j])*gwL[512+c0+j];
            S8U A, U, Pd;
#pragma unroll
            for (int p = 0; p < 4; ++p) {
                A.u[p]  = pkrn(ea[2*p], ea[2*p+1]);
                U.u[p]  = pkrn(eu[2*p], eu[2*p+1]);
                Pd.u[p] = pkrn(ea[2*p]*eu[2*p], ea[2*p+1]*eu[2*p+1]);
            }
            za[mt] = A.v; zb[mt] = U.v; zc[mt] = Pd.v;
        }
#pragma unroll
        for (int nt = 0; nt < 4; ++nt) {
            const int ntg = w*4 + nt;
            const size_t f0 = ((size_t)((kc*3 + 0)*16 + ntg)*64 + lane)*4;
            const size_t f1 = ((size_t)((kc*3 + 1)*16 + ntg)*64 + lane)*4;
            const size_t f2 = ((size_t)((kc*3 + 2)*16 + ntg)*64 + lane)*4;
            s8_t w0h = *(const s8_t*)(Whi + f0), w0l = *(const s8_t*)(Wlo + f0);
            s8_t w1h = *(const s8_t*)(Whi + f1), w1l = *(const s8_t*)(Wlo + f1);
            s8_t w2h = *(const s8_t*)(Whi + f2), w2l = *(const s8_t*)(Wlo + f2);
#pragma unroll
            for (int mt = 0; mt < 4; ++mt) {
                acc[mt][nt] = __builtin_amdgcn_mfma_f32_16x16x32_bf16(za[mt], w0h, acc[mt][nt], 0,0,0);
                acc[mt][nt] = __builtin_amdgcn_mfma_f32_16x16x32_bf16(za[mt], w0l, acc[mt][nt], 0,0,0);
                acc[mt][nt] = __builtin_amdgcn_mfma_f32_16x16x32_bf16(zb[mt], w1h, acc[mt][nt], 0,0,0);
                acc[mt][nt] = __builtin_amdgcn_mfma_f32_16x16x32_bf16(zb[mt], w1l, acc[mt][nt], 0,0,0);
                acc[mt][nt] = __builtin_amdgcn_mfma_f32_16x16x32_bf16(zc[mt], w2h, acc[mt][nt], 0,0,0);
                acc[mt][nt] = __builtin_amdgcn_mfma_f32_16x16x32_bf16(zc[mt], w2l, acc[mt][nt], 0,0,0);
            }
        }
    }

    // gate reduce over the 4 quad lanes; wave 0 publishes
#pragma unroll
    for (int mt = 0; mt < 4; ++mt) {
        float gg = gp[mt];
        gg += __shfl_xor(gg, 16, 64);
        gg += __shfl_xor(gg, 32, 64);
        if (w == 0 && quad == 0) gv[16*mt + il] = gg;
    }
    __syncthreads();
    if (tid < 64) gv[tid] = 1.0f / (1.0f + __expf(-(gv[tid] + bg[0])));
    __syncthreads();

    // epilogue: row = 16mt + 4quad + b, col = 64w + 16nt + il
#pragma unroll
    for (int nt = 0; nt < 4; ++nt) {
        const int col = w*64 + nt*16 + il;
        const float bfv = bf[col];
#pragma unroll
        for (int mt = 0; mt < 4; ++mt) {
#pragma unroll
            for (int b = 0; b < 4; ++b) {
                const int r = 16*mt + 4*quad + b;
                const float g = gv[r];
                const float cc = c2b[(size_t)r*DD + col];
                out[(row0 + r)*DD + col] = g * tanhf(acc[mt][nt][b] + bfv) + (1.f - g) * cc;
            }
        }
    }
}

extern "C" void kernel_launch(void* const* d_in, const int* in_sizes, int n_in,
                              void* d_out, int out_size, void* d_ws, size_t ws_size,
                              hipStream_t stream)
{
    const float* c1 = (const float*)d_in[0];
    const float* c2 = (const float*)d_in[1];
    const unsigned char* cmask = (const unsigned char*)d_in[2];
    const float* Wf = (const float*)d_in[3];
    const float* bf = (const float*)d_in[4];
    const float* Wg = (const float*)d_in[5];
    const float* bg = (const float*)d_in[6];

    // EXACT R3 ws layout: Op[2*16384*256] | mlp[2*16384*2] | aug[16384*256]
    // Wfrag (Whi/Wlo/gw) ALIASES Op: prep runs after combine, when Op is dead.
    const size_t opart_elems = (size_t)2 * 16384 * 256;
    const size_t ml_elems    = (size_t)2 * 16384 * 2;
    const size_t aug_elems   = (size_t)16384 * 256;
    const size_t frag_elems  = (size_t)98304;   // uints per buffer
    const size_t need_split  = (opart_elems + ml_elems + aug_elems) * sizeof(float);
    const int split = (ws_size >= need_split) ? 1 : 0;

    float* wsf = (float*)d_ws;
    float *Op, *mlp, *aug;
    unsigned *Whi, *Wlo; float *gw;
    if (split) {
        Op  = wsf; mlp = wsf + opart_elems; aug = mlp + ml_elems;
        Whi = (unsigned*)Op; Wlo = Whi + frag_elems; gw = (float*)(Wlo + frag_elems);
    } else {
        Op  = wsf; mlp = wsf; aug = wsf;
        Whi = (unsigned*)(wsf + aug_elems); Wlo = Whi + frag_elems; gw = (float*)(Wlo + frag_elems);
    }

    if (split) {
        attn_kernel<<<dim3(256), dim3(256), 0, stream>>>(c1, c2, cmask, Op, mlp, 1024, 1);
        combine_kernel<<<dim3(4096), dim3(256), 0, stream>>>(Op, mlp, aug);
        prep_kernel<<<dim3(385), dim3(256), 0, stream>>>(Wf, Wg, Whi, Wlo, gw);
        fusion_mfma<<<dim3(256), dim3(256), 0, stream>>>(c2, aug, Whi, Wlo, gw, bg, bf, (float*)d_out);
    } else {
        attn_kernel<<<dim3(128), dim3(256), 0, stream>>>(c1, c2, cmask, aug, mlp, 2048, 0);
        prep_kernel<<<dim3(385), dim3(256), 0, stream>>>(Wf, Wg, Whi, Wlo, gw);
        fusion_mfma<<<dim3(256), dim3(256), 0, stream>>>(c2, aug, Whi, Wlo, gw, bg, bf, (float*)d_out);
    }
}